// Round 6
// baseline (60.439 us; speedup 1.0000x reference)
//
#include <hip/hip_runtime.h>

// Batched Thomas tridiagonal solve, B=8192 rows, N=4096.
//   a_i = alpha[i-1]^2 (a_0=0); b_i = max(5+alpha[i]^3, 0.01);
//   c_i = alpha[i+1]^2 + 2*alpha[i+1]; rhs f (shared across rows).
//
// Chunked UL elimination with halos (diag dominant: backward decay <=0.70/step
// -> right halo H=32 err ~1e-5; forward decay <=0.235/step -> left halo HL=8).
//
// R6: fix R5's 12.2M bank conflicts. Conflicts resolve per 16-lane quarter-
// wave; R5's lane map (j=lane>>3) gave each quarter-wave only 2 rows x 8
// chunks, and chunk offset q*32 dw == 0 mod 32 -> 8 lanes per bank, 8-way
// conflict on every A/f read. New map j=lane&7, q=lane>>3: quarter-wave = 8
// distinct rows (8 distinct banks via 308-dw row stride) x 2 chunks (2-way =
// free). Nothing else changed vs R5.

namespace {
constexpr int kN   = 4096;
constexpr int kCH  = 32;              // outputs per lane
constexpr int kHL  = 8;               // left halo
constexpr int kR   = kCH + kHL;       // stored region = 40
constexpr int kNC  = kN / kCH;        // 128 chunks per row
constexpr int RPW  = 8;               // rows per wave
constexpr int CPW  = 8;               // chunks per wave (256-col window)
constexpr int WAVES = 2;
constexpr int THREADS = 64 * WAVES;   // 128
constexpr int F4PR = 76;              // staged f4 per row: cols [base-12, base+292)
constexpr int ST4  = 77;              // row stride in f4 (308 dw; 308%32==20)
constexpr int WLDS4 = RPW * ST4 + F4PR;  // 692 f4 per wave (A panel + f span)
}

__global__ __launch_bounds__(THREADS) void thomas_v6(
    const float4* __restrict__ alpha4,
    const float4* __restrict__ f4,
    float4* __restrict__ u4)
{
  __shared__ float4 sM[WAVES * WLDS4];   // 22144 B

  const int bid  = blockIdx.x;
  const int cw   = bid & 15;                    // col window (256 cols)
  const int r0   = (bid >> 4) * (WAVES * RPW);  // first row of block
  const int tid  = threadIdx.x;
  const int w    = tid >> 6;
  const int lane = tid & 63;
  const int cbase4 = cw * 64 - 3;               // first staged global f4 col

  float4* __restrict__ sA = sM + w * WLDS4;             // [RPW][ST4]
  float4* __restrict__ sF = sM + w * WLDS4 + RPW * ST4; // [F4PR]

  // ---- wave-private staging (coalesced float4, reg->LDS) ----
  const int rw0 = r0 + w * RPW;
  #pragma unroll
  for (int it = 0; it < 10; ++it) {
    const int idx = lane + it * 64;
    if (idx < RPW * F4PR) {                      // 608
      const int row = idx / F4PR;
      const int c4  = idx - row * F4PR;
      int g4 = cbase4 + c4;
      g4 = (g4 < 0) ? 0 : ((g4 > kN / 4 - 1) ? kN / 4 - 1 : g4);  // dups unused
      sA[row * ST4 + c4] = alpha4[(size_t)(rw0 + row) * (kN / 4) + g4];
    }
  }
  #pragma unroll
  for (int it = 0; it < 2; ++it) {
    const int idx = lane + it * 64;
    if (idx < F4PR) {
      int g4 = cbase4 + idx;
      g4 = (g4 < 0) ? 0 : ((g4 > kN / 4 - 1) ? kN / 4 - 1 : g4);
      sF[idx] = f4[g4];
    }
  }
  // no __syncthreads: wave reads only its own region (lockstep + lgkmcnt)

  // ---- per-lane chunk solve ----
  const int j = lane & 7;                  // row-local 0..7  (quarter-wave: 8 rows)
  const int q = lane >> 3;                 // chunk-local 0..7
  const int k = cw * CPW + q;
  const bool first = (k == 0);
  const bool last  = (k == kNC - 1);
  const int  f4b = first ? 3 : (q * 8 + 1);  // = (sL + 12 - base)/4

  const float4* __restrict__ A4 = sA + j * ST4;
  const float4* __restrict__ F4 = sF;

  float gp[kR], ep[kR];
  float ec = 0.0f, gc = 0.0f, ap1 = 0.0f;  // zero carry: first step's c*carry=0
  const int ghi = last ? 9 : 17;
  float4 curA = A4[f4b + ghi];
  float4 lowA = A4[f4b + ghi - 1];
  float4 fcur = F4[f4b + ghi];
  float4 flow = F4[f4b + ghi - 1];
  float a0 = curA.w;

#define STEP(am1v, fiv)                                        \
  {                                                            \
    const float c_  = ap1 * (ap1 + 2.0f);                      \
    const float b_  = fmaxf(fmaf(a0 * a0, a0, 5.0f), 0.01f);   \
    const float dn  = fmaf(-c_, ec, b_);                       \
    const float rd  = __builtin_amdgcn_rcpf(dn);               \
    gc = (fiv - c_ * gc) * rd;                                 \
    ec = ((am1v) * (am1v)) * rd;                               \
    ap1 = a0; a0 = (am1v);                                     \
  }

  // Phase A: right-halo descend, groups 17..10 (no stores)
  if (!last) {
    #pragma unroll
    for (int g = 17; g >= 10; --g) {
      const float4 pA = A4[f4b + g - 2];
      const float4 pF = F4[f4b + g - 2];
      STEP(curA.z, fcur.w)
      STEP(curA.y, fcur.z)
      STEP(curA.x, fcur.y)
      STEP(lowA.w, fcur.x)
      curA = lowA; lowA = pA; fcur = flow; flow = pF;
    }
  }

  // Phase B: stored sweep, groups 9..0
  #pragma unroll
  for (int g = 9; g >= 0; --g) {
    int pidx = f4b + g - 2;
    if (pidx < 0) pidx = 0;                // value unused when clamped
    const float4 pA = A4[pidx];
    const float4 pF = F4[pidx];
    float lw = lowA.w;
    if (g == 0 && first) lw = 0.0f;        // a_0 = 0
    STEP(curA.z, fcur.w)  gp[4*g+3] = gc; ep[4*g+3] = ec;
    STEP(curA.y, fcur.z)  gp[4*g+2] = gc; ep[4*g+2] = ec;
    STEP(curA.x, fcur.y)  gp[4*g+1] = gc; ep[4*g+1] = ec;
    STEP(lw,     fcur.x)  gp[4*g+0] = gc; ep[4*g+0] = ec;
    curA = lowA; lowA = pA; fcur = flow; flow = pF;
  }
#undef STEP

  // ---- substitution into wave-private out-tile (overlays sA; all LDS reads
  // of this wave are complete in program order, lockstep => no race) ----
  const int tmin = first ? 0 : kHL;
  float up = 0.0f;
  float4 pk;
  #pragma unroll
  for (int t = 0; t < kR; ++t) {
    const float uv = fmaf(-ep[t], up, gp[t]);
    up = uv;
    const int ph = t & 3;
    if      (ph == 0) pk.x = uv;
    else if (ph == 1) pk.y = uv;
    else if (ph == 2) pk.z = uv;
    else {
      pk.w = uv;
      if (t - 3 >= tmin && t < tmin + kCH) {
        sA[j * ST4 + q * 8 + ((t - 3 - tmin) >> 2)] = pk;
      }
    }
  }

  // ---- coalesced dump: one full 1KB row-segment per store instruction ----
  #pragma unroll
  for (int it = 0; it < RPW; ++it) {
    const float4 v = sA[it * ST4 + lane];
    u4[(size_t)(rw0 + it) * (kN / 4) + cw * 64 + lane] = v;
  }
}

extern "C" void kernel_launch(void* const* d_in, const int* in_sizes, int n_in,
                              void* d_out, int out_size, void* d_ws, size_t ws_size,
                              hipStream_t stream) {
  const float4* alpha = (const float4*)d_in[0];
  const float4* f     = (const float4*)d_in[1];
  float4*       uo    = (float4*)d_out;
  // grid: 512 row-groups (16 rows) x 16 col-windows (256 cols) = 8192 blocks
  thomas_v6<<<dim3(8192), THREADS, 0, stream>>>(alpha, f, uo);
}

// Round 7
// 55.031 us; speedup vs baseline: 1.0983x; 1.0983x over previous
//
#include <hip/hip_runtime.h>

// Batched Thomas tridiagonal solve, B=8192 rows, N=4096.
//   a_i = alpha[i-1]^2 (a_0=0); b_i = max(5+alpha[i]^3, 0.01);
//   c_i = alpha[i+1]^2 + 2*alpha[i+1]; rhs f (shared across rows).
//
// Chunked UL elimination with halos (diag dominant: backward decay <=0.70/step
// -> right halo H=32 err ~1e-5; forward decay <=0.235/step -> left halo HL=8).
//
// R7: two-tile pipeline per wave (T14 issue-early/write-late). R6 showed wall
// = VALU floor + HBM stalls summed (no overlap at 2.4 waves/SIMD). Each wave
// now solves col-windows 2p and 2p+1: T1's global loads are issued into
// registers BEFORE T0's compute, drained to LDS after T0's dump -> T1 stage
// latency hides under T0 compute. sF covers the 512-col pair, shared by both
// waves (idempotent writes, no barrier). Math identical (absmax anchor
// 0.00390625).

namespace {
constexpr int kN   = 4096;
constexpr int kCH  = 32;              // outputs per lane
constexpr int kHL  = 8;               // left halo
constexpr int kR   = kCH + kHL;       // stored region = 40
constexpr int kNC  = kN / kCH;        // 128 chunks per row
constexpr int RPW  = 8;               // rows per wave
constexpr int WAVES = 2;
constexpr int THREADS = 64 * WAVES;   // 128
constexpr int F4PR = 76;              // per-tile staged f4/row: [cb-12, cb+292)
constexpr int ST4  = 77;              // A row stride in f4 (308 dw; %32==20)
constexpr int APW4 = RPW * ST4;       // 616 f4 per wave A panel
constexpr int SF4  = 141;             // shared f window: 140 f4 + pad
}

__global__ __launch_bounds__(THREADS) void thomas_v7(
    const float4* __restrict__ alpha4,
    const float4* __restrict__ f4,
    float4* __restrict__ u4)
{
  __shared__ float4 sM[WAVES * APW4 + SF4];   // 1373 f4 = 21968 B

  const int bid  = blockIdx.x;
  const int pair = bid & 7;                     // 512-col window pair
  const int r0   = (bid >> 3) * (WAVES * RPW);
  const int w    = threadIdx.x >> 6;
  const int lane = threadIdx.x & 63;
  const int rw0  = r0 + w * RPW;
  const int j    = lane & 7;                    // row-local (quarter-wave: 8 rows)
  const int q    = lane >> 3;                   // chunk-local 0..7

  float4* __restrict__ sA = sM + w * APW4;      // wave-private [RPW][ST4]
  float4* __restrict__ sF = sM + WAVES * APW4;  // block-shared f pair window

#define LOAD_TILE(cw, P)                                              \
  {                                                                   \
    const int cb4 = (cw) * 64 - 3;                                    \
    _Pragma("unroll")                                                 \
    for (int it = 0; it < 10; ++it) {                                 \
      int idx = lane + it * 64;                                       \
      if (idx > RPW * F4PR - 1) idx = RPW * F4PR - 1;  /* dup */      \
      const int row = idx / F4PR;                                     \
      const int c4  = idx - row * F4PR;                               \
      int g4 = cb4 + c4;                                              \
      g4 = (g4 < 0) ? 0 : ((g4 > 1023) ? 1023 : g4);  /* dups unused */ \
      P[it] = alpha4[(size_t)(rw0 + row) * 1024 + g4];                \
    }                                                                 \
  }

#define WRITE_TILE(P)                                                 \
  {                                                                   \
    _Pragma("unroll")                                                 \
    for (int it = 0; it < 10; ++it) {                                 \
      const int idx = lane + it * 64;                                 \
      if (idx < RPW * F4PR) {                                         \
        const int row = idx / F4PR;                                   \
        const int c4  = idx - row * F4PR;                             \
        sA[row * ST4 + c4] = P[it];                                   \
      }                                                               \
    }                                                                 \
  }

#define STEP(am1v, fiv)                                        \
  {                                                            \
    const float c_  = ap1 * (ap1 + 2.0f);                      \
    const float b_  = fmaxf(fmaf(a0 * a0, a0, 5.0f), 0.01f);   \
    const float dn  = fmaf(-c_, ec, b_);                       \
    const float rd  = __builtin_amdgcn_rcpf(dn);               \
    gc = (fiv - c_ * gc) * rd;                                 \
    ec = ((am1v) * (am1v)) * rd;                               \
    ap1 = a0; a0 = (am1v);                                     \
  }

  // Solve one tile from sA/sF; CWL is a compile-time 0/1.
#define SOLVE_TILE(CWL)                                                   \
  {                                                                       \
    const int  kk    = (pair * 2 + (CWL)) * 8 + q;                        \
    const bool first = (kk == 0);                                         \
    const bool last  = (kk == kNC - 1);                                   \
    const int  f4b   = first ? 3 : (q * 8 + 1);                           \
    const int  fOff  = (CWL) * 64;                                        \
    const float4* __restrict__ A4 = sA + j * ST4;                         \
    float gp[kR], ep[kR];                                                 \
    float ec = 0.0f, gc = 0.0f, ap1 = 0.0f;                               \
    const int ghi = last ? 9 : 17;                                        \
    float4 curA = A4[f4b + ghi];                                          \
    float4 lowA = A4[f4b + ghi - 1];                                      \
    float4 fcur = sF[fOff + f4b + ghi];                                   \
    float4 flow = sF[fOff + f4b + ghi - 1];                               \
    float a0 = curA.w;                                                    \
    if (!last) {                                                          \
      _Pragma("unroll")                                                   \
      for (int g = 17; g >= 10; --g) {                                    \
        const float4 pA = A4[f4b + g - 2];                                \
        const float4 pF = sF[fOff + f4b + g - 2];                         \
        STEP(curA.z, fcur.w)                                              \
        STEP(curA.y, fcur.z)                                              \
        STEP(curA.x, fcur.y)                                              \
        STEP(lowA.w, fcur.x)                                              \
        curA = lowA; lowA = pA; fcur = flow; flow = pF;                   \
      }                                                                   \
    }                                                                     \
    _Pragma("unroll")                                                     \
    for (int g = 9; g >= 0; --g) {                                        \
      int pidx = f4b + g - 2;                                             \
      if (pidx < 0) pidx = 0;            /* value unused when clamped */  \
      const float4 pA = A4[pidx];                                         \
      const float4 pF = sF[fOff + pidx];                                  \
      float lw = lowA.w;                                                  \
      if (g == 0 && first) lw = 0.0f;    /* a_0 = 0 */                    \
      STEP(curA.z, fcur.w)  gp[4*g+3] = gc; ep[4*g+3] = ec;               \
      STEP(curA.y, fcur.z)  gp[4*g+2] = gc; ep[4*g+2] = ec;               \
      STEP(curA.x, fcur.y)  gp[4*g+1] = gc; ep[4*g+1] = ec;               \
      STEP(lw,     fcur.x)  gp[4*g+0] = gc; ep[4*g+0] = ec;               \
      curA = lowA; lowA = pA; fcur = flow; flow = pF;                     \
    }                                                                     \
    const int tmin = first ? 0 : kHL;                                     \
    float up = 0.0f;                                                      \
    float4 pk;                                                            \
    _Pragma("unroll")                                                     \
    for (int t = 0; t < kR; ++t) {                                        \
      const float uv = fmaf(-ep[t], up, gp[t]);                           \
      up = uv;                                                            \
      const int ph = t & 3;                                               \
      if      (ph == 0) pk.x = uv;                                        \
      else if (ph == 1) pk.y = uv;                                        \
      else if (ph == 2) pk.z = uv;                                        \
      else {                                                              \
        pk.w = uv;                                                        \
        if (t - 3 >= tmin && t < tmin + kCH) {                            \
          sA[j * ST4 + q * 8 + ((t - 3 - tmin) >> 2)] = pk;               \
        }                                                                 \
      }                                                                   \
    }                                                                     \
    _Pragma("unroll")                                                     \
    for (int it = 0; it < RPW; ++it) {                                    \
      const float4 v = sA[it * ST4 + lane];                               \
      u4[(size_t)(rw0 + it) * 1024 + (pair * 2 + (CWL)) * 64 + lane] = v; \
    }                                                                     \
  }

  // ---- shared f window (idempotent writes by both waves; no barrier) ----
  {
    const int fb4 = pair * 128 - 3;
    #pragma unroll
    for (int it = 0; it < 3; ++it) {
      const int idx = lane + it * 64;
      if (idx < 140) {
        int g4 = fb4 + idx;
        g4 = (g4 < 0) ? 0 : ((g4 > 1023) ? 1023 : g4);
        sF[idx] = f4[g4];
      }
    }
  }

  // ---- two-tile pipeline ----
  float4 p0[10];
  LOAD_TILE(pair * 2, p0)
  WRITE_TILE(p0)

  float4 p1[10];
  LOAD_TILE(pair * 2 + 1, p1)   // issued BEFORE T0 compute (latency hidden)

  SOLVE_TILE(0)                 // compute + subst + dump T0

  WRITE_TILE(p1)                // vmcnt drain here, after T0 dump reads

  SOLVE_TILE(1)

#undef LOAD_TILE
#undef WRITE_TILE
#undef STEP
#undef SOLVE_TILE
}

extern "C" void kernel_launch(void* const* d_in, const int* in_sizes, int n_in,
                              void* d_out, int out_size, void* d_ws, size_t ws_size,
                              hipStream_t stream) {
  const float4* alpha = (const float4*)d_in[0];
  const float4* f     = (const float4*)d_in[1];
  float4*       uo    = (float4*)d_out;
  // grid: 512 row-groups (16 rows) x 8 window-pairs (512 cols) = 4096 blocks
  thomas_v7<<<dim3(4096), THREADS, 0, stream>>>(alpha, f, uo);
}